// Round 1
// baseline (908.482 us; speedup 1.0000x reference)
//
#include <hip/hip_runtime.h>

constexpr int MBS = 16, HD = 64, NMB = 256;
constexpr int XS = 68;   // padded LDS row stride for 16x64 tiles (breaks bank conflicts)

__global__ __launch_bounds__(256) void ttt_scan(
    const float* __restrict__ gXQ, const float* __restrict__ gXK,
    const float* __restrict__ gXV, const float* __restrict__ gETA,
    const float* __restrict__ gW1, const float* __restrict__ gB1,
    const float* __restrict__ gLNW, const float* __restrict__ gLNB,
    float* __restrict__ gOUT)
{
    __shared__ float sW[HD * HD];                                   // 16 KB, stride 64
    __shared__ float sXQ[MBS * XS], sXK[MBS * XS], sXV[MBS * XS];   // padded tiles
    __shared__ float sG[MBS * XS];
    __shared__ float sEta[MBS * MBS], sEtA[MBS * MBS];
    __shared__ float sB1[HD];

    const int t = threadIdx.x;
    const int s = t >> 4;        // row 0..15
    const int dt = t & 15;       // col group (4 cols each)
    const int bh = blockIdx.x;
    const int b = bh >> 3, h = bh & 7;

    const float* xqg = gXQ + (size_t)bh * (NMB * MBS * HD);
    const float* xkg = gXK + (size_t)bh * (NMB * MBS * HD);
    const float* xvg = gXV + (size_t)bh * (NMB * MBS * HD);
    const float* etg = gETA + (size_t)bh * (NMB * MBS * MBS);

    // ---- init state: W1[h] -> LDS, b1[h] -> LDS ----
#pragma unroll
    for (int i = 0; i < 4; ++i) {
        const int idx = (i * 256 + t) * 4;
        *(float4*)&sW[idx] = *(const float4*)&gW1[h * HD * HD + idx];
    }
    if (t < 16) *(float4*)&sB1[t * 4] = *(const float4*)&gB1[h * HD + t * 4];
    __syncthreads();

    // per-thread register tile of W: rows 4s..4s+3, cols 4dt..4dt+3
    float4 wreg[4];
#pragma unroll
    for (int r = 0; r < 4; ++r) wreg[r] = *(float4*)&sW[(4 * s + r) * HD + dt * 4];

    const float4 gam = *(const float4*)&gLNW[h * HD + dt * 4];
    const float4 bet = *(const float4*)&gLNB[h * HD + dt * 4];

    // prefetch minibatch 0 into registers
    float4 pq = *(const float4*)&xqg[t * 4];
    float4 pk = *(const float4*)&xkg[t * 4];
    float4 pv = *(const float4*)&xvg[t * 4];
    float4 pe = make_float4(0.f, 0.f, 0.f, 0.f);
    if (t < 64) pe = *(const float4*)&etg[t * 4];

    for (int m = 0; m < NMB; ++m) {
        __syncthreads();   // prev step's state writes / LDS reads complete
        *(float4*)&sXQ[s * XS + dt * 4] = pq;
        *(float4*)&sXK[s * XS + dt * 4] = pk;
        *(float4*)&sXV[s * XS + dt * 4] = pv;
        if (t < 64) *(float4*)&sEta[t * 4] = pe;
        __syncthreads();

        // async prefetch of next minibatch (hides HBM latency under compute)
        if (m + 1 < NMB) {
            const size_t o = (size_t)(m + 1) * (MBS * HD) + t * 4;
            pq = *(const float4*)&xqg[o];
            pk = *(const float4*)&xkg[o];
            pv = *(const float4*)&xvg[o];
            if (t < 64) pe = *(const float4*)&etg[(size_t)(m + 1) * (MBS * MBS) + t * 4];
        }

        // ======== Phase A: Z1 = xk@W + b1 ; Zq = xq@W ; Attn[s][dt] ========
        const float4 b1v = *(float4*)&sB1[dt * 4];
        float z0 = b1v.x, z1 = b1v.y, z2 = b1v.z, z3 = b1v.w;
        float q0 = 0.f, q1 = 0.f, q2 = 0.f, q3 = 0.f;
        float attn = 0.f;
#pragma unroll 16
        for (int k = 0; k < HD; ++k) {
            const float xkk = sXK[s * XS + k];
            const float xqk = sXQ[s * XS + k];
            const float xkd = sXK[dt * XS + k];
            const float4 wv = *(float4*)&sW[k * HD + dt * 4];
            z0 = fmaf(xkk, wv.x, z0); z1 = fmaf(xkk, wv.y, z1);
            z2 = fmaf(xkk, wv.z, z2); z3 = fmaf(xkk, wv.w, z3);
            q0 = fmaf(xqk, wv.x, q0); q1 = fmaf(xqk, wv.y, q1);
            q2 = fmaf(xqk, wv.z, q2); q3 = fmaf(xqk, wv.w, q3);
            attn = fmaf(xqk, xkd, attn);
        }
        const float ev = sEta[s * 16 + dt];
        sEtA[s * 16 + dt] = (dt <= s) ? attn * ev : 0.f;   // (eta*Attn1), tril-masked

        // ---- LN-bwd (fused l2) on Z1 -> g ----
        float sum = z0 + z1 + z2 + z3;
        float sq  = z0 * z0 + z1 * z1 + z2 * z2 + z3 * z3;
#pragma unroll
        for (int msk = 1; msk < 16; msk <<= 1) {
            sum += __shfl_xor(sum, msk);
            sq  += __shfl_xor(sq, msk);
        }
        const float mu   = sum * (1.f / 64.f);
        const float rstd = rsqrtf(sq * (1.f / 64.f) - mu * mu + 1e-6f);
        const float xh0 = (z0 - mu) * rstd, xh1 = (z1 - mu) * rstd;
        const float xh2 = (z2 - mu) * rstd, xh3 = (z3 - mu) * rstd;
        const float4 xv4 = *(float4*)&sXV[s * XS + dt * 4];
        const float4 xk4 = *(float4*)&sXK[s * XS + dt * 4];
        const float gx0 = (fmaf(gam.x, xh0, bet.x) - (xv4.x - xk4.x)) * gam.x;
        const float gx1 = (fmaf(gam.y, xh1, bet.y) - (xv4.y - xk4.y)) * gam.y;
        const float gx2 = (fmaf(gam.z, xh2, bet.z) - (xv4.z - xk4.z)) * gam.z;
        const float gx3 = (fmaf(gam.w, xh3, bet.w) - (xv4.w - xk4.w)) * gam.w;
        float r1 = gx0 + gx1 + gx2 + gx3;
        float r2 = gx0 * xh0 + gx1 * xh1 + gx2 * xh2 + gx3 * xh3;
#pragma unroll
        for (int msk = 1; msk < 16; msk <<= 1) {
            r1 += __shfl_xor(r1, msk);
            r2 += __shfl_xor(r2, msk);
        }
        const float cfac = rstd * (1.f / 64.f);
        const float g0 = (64.f * gx0 - r1 - xh0 * r2) * cfac;
        const float g1 = (64.f * gx1 - r1 - xh1 * r2) * cfac;
        const float g2 = (64.f * gx2 - r1 - xh2 * r2) * cfac;
        const float g3 = (64.f * gx3 - r1 - xh3 * r2) * cfac;
        *(float4*)&sG[s * XS + dt * 4] = make_float4(g0, g1, g2, g3);
        __syncthreads();   // g, etA visible

        // ======== Phase B: Z1_bar, output ========
        float a10 = 0.f, a11 = 0.f, a12 = 0.f, a13 = 0.f;   // (tril*eta)@g
        float a20 = 0.f, a21 = 0.f, a22 = 0.f, a23 = 0.f;   // (eta*Attn1)@g
#pragma unroll
        for (int j = 0; j < 16; ++j) {
            const float e1 = (j <= s) ? sEta[s * 16 + j] : 0.f;
            const float e2 = sEtA[s * 16 + j];
            const float4 gj = *(float4*)&sG[j * XS + dt * 4];
            a10 = fmaf(e1, gj.x, a10); a11 = fmaf(e1, gj.y, a11);
            a12 = fmaf(e1, gj.z, a12); a13 = fmaf(e1, gj.w, a13);
            a20 = fmaf(e2, gj.x, a20); a21 = fmaf(e2, gj.y, a21);
            a22 = fmaf(e2, gj.z, a22); a23 = fmaf(e2, gj.w, a23);
        }
        const float zb0 = q0 - a20 + (b1v.x - a10);
        const float zb1 = q1 - a21 + (b1v.y - a11);
        const float zb2 = q2 - a22 + (b1v.z - a12);
        const float zb3 = q3 - a23 + (b1v.w - a13);

        float sb  = zb0 + zb1 + zb2 + zb3;
        float sb2 = zb0 * zb0 + zb1 * zb1 + zb2 * zb2 + zb3 * zb3;
#pragma unroll
        for (int msk = 1; msk < 16; msk <<= 1) {
            sb  += __shfl_xor(sb, msk);
            sb2 += __shfl_xor(sb2, msk);
        }
        const float mu2   = sb * (1.f / 64.f);
        const float rstd2 = rsqrtf(sb2 * (1.f / 64.f) - mu2 * mu2 + 1e-6f);
        const float4 xq4 = *(float4*)&sXQ[s * XS + dt * 4];
        const float o0 = xq4.x + fmaf(gam.x, (zb0 - mu2) * rstd2, bet.x);
        const float o1 = xq4.y + fmaf(gam.y, (zb1 - mu2) * rstd2, bet.y);
        const float o2 = xq4.z + fmaf(gam.z, (zb2 - mu2) * rstd2, bet.z);
        const float o3 = xq4.w + fmaf(gam.w, (zb3 - mu2) * rstd2, bet.w);
        const size_t oi = ((size_t)b * 4096 + (size_t)m * 16 + s) * 512 + h * 64 + dt * 4;
        *(float4*)&gOUT[oi] = make_float4(o0, o1, o2, o3);

        // ======== Phase C: state update (no barrier needed: B reads none of sW/sB1) ========
        float bc0 = 0.f, bc1 = 0.f, bc2 = 0.f, bc3 = 0.f;
#pragma unroll
        for (int j = 0; j < 16; ++j) {
            const float le = sEta[15 * 16 + j];      // last row of eta
            const float4 gj = *(float4*)&sG[j * XS + dt * 4];
            const float k0 = sXK[j * XS + 4 * s + 0];
            const float k1 = sXK[j * XS + 4 * s + 1];
            const float k2 = sXK[j * XS + 4 * s + 2];
            const float k3 = sXK[j * XS + 4 * s + 3];
            const float t0 = le * k0, t1 = le * k1, t2 = le * k2, t3 = le * k3;
            wreg[0].x = fmaf(-t0, gj.x, wreg[0].x); wreg[0].y = fmaf(-t0, gj.y, wreg[0].y);
            wreg[0].z = fmaf(-t0, gj.z, wreg[0].z); wreg[0].w = fmaf(-t0, gj.w, wreg[0].w);
            wreg[1].x = fmaf(-t1, gj.x, wreg[1].x); wreg[1].y = fmaf(-t1, gj.y, wreg[1].y);
            wreg[1].z = fmaf(-t1, gj.z, wreg[1].z); wreg[1].w = fmaf(-t1, gj.w, wreg[1].w);
            wreg[2].x = fmaf(-t2, gj.x, wreg[2].x); wreg[2].y = fmaf(-t2, gj.y, wreg[2].y);
            wreg[2].z = fmaf(-t2, gj.z, wreg[2].z); wreg[2].w = fmaf(-t2, gj.w, wreg[2].w);
            wreg[3].x = fmaf(-t3, gj.x, wreg[3].x); wreg[3].y = fmaf(-t3, gj.y, wreg[3].y);
            wreg[3].z = fmaf(-t3, gj.z, wreg[3].z); wreg[3].w = fmaf(-t3, gj.w, wreg[3].w);
            bc0 = fmaf(le, gj.x, bc0); bc1 = fmaf(le, gj.y, bc1);
            bc2 = fmaf(le, gj.z, bc2); bc3 = fmaf(le, gj.w, bc3);
        }
#pragma unroll
        for (int r = 0; r < 4; ++r)
            *(float4*)&sW[(4 * s + r) * HD + dt * 4] = wreg[r];
        if (s == 0)
            *(float4*)&sB1[dt * 4] =
                make_float4(b1v.x - bc0, b1v.y - bc1, b1v.z - bc2, b1v.w - bc3);
    }
}

extern "C" void kernel_launch(void* const* d_in, const int* in_sizes, int n_in,
                              void* d_out, int out_size, void* d_ws, size_t ws_size,
                              hipStream_t stream) {
    const float* XQ  = (const float*)d_in[0];
    const float* XK  = (const float*)d_in[1];
    const float* XV  = (const float*)d_in[2];
    const float* ETA = (const float*)d_in[3];
    const float* W1  = (const float*)d_in[4];
    const float* B1  = (const float*)d_in[5];
    const float* LNW = (const float*)d_in[6];
    const float* LNB = (const float*)d_in[7];
    float* OUT = (float*)d_out;

    const int n_chains = in_sizes[0] / (NMB * MBS * HD);   // B*nh = 64
    ttt_scan<<<n_chains, 256, 0, stream>>>(XQ, XK, XV, ETA, W1, B1, LNW, LNB, OUT);
}

// Round 4
// 509.427 us; speedup vs baseline: 1.7833x; 1.7833x over previous
//
#include <hip/hip_runtime.h>

typedef __attribute__((ext_vector_type(8))) short short8;
typedef __attribute__((ext_vector_type(4))) short short4_t;
typedef __attribute__((ext_vector_type(4))) float f32x4;

constexpr int MBS = 16, HD = 64, NMB = 256;

#define MFMA(a, b, c) __builtin_amdgcn_mfma_f32_16x16x32_bf16(a, b, c, 0, 0, 0)
#define TR_READ(dst, addr, IMM) \
    asm volatile("ds_read_b64_tr_b16 %0, %1 offset:" IMM : "=v"(dst) : "v"(addr))

__device__ inline short f2bf(float x) {
    union { float f; unsigned u; } v; v.f = x;
    unsigned r = (v.u + 0x7fffu + ((v.u >> 16) & 1u)) >> 16;
    return (short)r;
}
__device__ inline short8 cmb(short4_t a, short4_t b) {
    short8 r;
    r[0]=a[0]; r[1]=a[1]; r[2]=a[2]; r[3]=a[3];
    r[4]=b[0]; r[5]=b[1]; r[6]=b[2]; r[7]=b[3];
    return r;
}

__global__ __launch_bounds__(256) void ttt_scan(
    const float* __restrict__ gXQ, const float* __restrict__ gXK,
    const float* __restrict__ gXV, const float* __restrict__ gETA,
    const float* __restrict__ gW1, const float* __restrict__ gB1,
    const float* __restrict__ gLNW, const float* __restrict__ gLNB,
    float* __restrict__ gOUT)
{
    // bf16 operand buffers
    __shared__ __align__(16) short sWt[64 * 72];   // W^T [n][k], stride 72
    __shared__ __align__(16) short bxk[16 * 72];   // xk bf16 [s][d]
    __shared__ __align__(16) short bxq[16 * 72];   // xq bf16 [s][d]
    // g and -le*xk in 4x16-tiled layout, jblk 0..7 (j=0..31; 16..31 permanently zero)
    __shared__ __align__(16) short sGt[2048];
    __shared__ __align__(16) short sXKe[2048];
    __shared__ __align__(16) short sE[16 * 40];    // -E [r][j], j zero-padded to 32
    // fp32 scratch
    __shared__ float sZ1[16 * 68];
    __shared__ float sZb[16 * 68];
    __shared__ float sXQ[16 * 68];
    __shared__ float sT2[16 * 68];   // gam*bet - gam*(xv-xk)
    __shared__ float sAttn[16 * 20];
    __shared__ float sEta[256];
    __shared__ float sB1[64];
    __shared__ float sB1p[4 * 64];

    const int t  = threadIdx.x;
    const int s  = t >> 4;        // thread-layout row
    const int dt = t & 15;        // thread-layout col-group (4 cols)
    const int lane = t & 63;
    const int w  = t >> 6;        // wave id
    const int gq = lane >> 4;     // 16-lane group within wave
    const int lc = lane & 15;
    const int bh = blockIdx.x;
    const int b = bh >> 3, h = bh & 7;

    const float* xqg = gXQ + (size_t)bh * (NMB * MBS * HD);
    const float* xkg = gXK + (size_t)bh * (NMB * MBS * HD);
    const float* xvg = gXV + (size_t)bh * (NMB * MBS * HD);
    const float* etg = gETA + (size_t)bh * (NMB * MBS * MBS);

    // ---- init: zero tiled/padded bf16 buffers (upper jblks stay zero forever) ----
    for (int i = t; i < 2048; i += 256) { sGt[i] = 0; sXKe[i] = 0; }
    for (int i = t; i < 16 * 40; i += 256) sE[i] = 0;

    // ---- init W state as MFMA C-fragments: wave w owns row-block [16w,16w+16) ----
    f32x4 Wacc[4];
#pragma unroll
    for (int ct = 0; ct < 4; ++ct) {
#pragma unroll
        for (int r = 0; r < 4; ++r)
            Wacc[ct][r] = gW1[h * 4096 + (16 * w + 4 * gq + r) * 64 + 16 * ct + lc];
        short4_t wp;
#pragma unroll
        for (int r = 0; r < 4; ++r) wp[r] = f2bf(Wacc[ct][r]);
        *(short4_t*)&sWt[(16 * ct + lc) * 72 + 16 * w + 4 * gq] = wp;
    }
    if (t < 64) sB1[t] = gB1[h * 64 + t];

    const float4 gam = *(const float4*)&gLNW[h * 64 + dt * 4];
    const float4 bet = *(const float4*)&gLNB[h * 64 + dt * 4];
    float4 c1, gb;
    c1.x = gam.x * gam.x; c1.y = gam.y * gam.y; c1.z = gam.z * gam.z; c1.w = gam.w * gam.w;
    gb.x = gam.x * bet.x; gb.y = gam.y * bet.y; gb.z = gam.z * bet.z; gb.w = gam.w * bet.w;

    // prefetch minibatch 0
    float4 pq = *(const float4*)&xqg[t * 4];
    float4 pk = *(const float4*)&xkg[t * 4];
    float4 pv = *(const float4*)&xvg[t * 4];
    float4 pe = make_float4(0.f, 0.f, 0.f, 0.f);
    if (t < 64) pe = *(const float4*)&etg[t * 4];
    float4 pkc;

    __syncthreads();

    for (int m = 0; m < NMB; ++m) {
        __syncthreads();   // (A) prev THREAD2 reads done
        // ======== STAGE ========
        *(float4*)&sXQ[s * 68 + dt * 4] = pq;
        float4 t2v;
        t2v.x = fmaf(-gam.x, pv.x - pk.x, gb.x);
        t2v.y = fmaf(-gam.y, pv.y - pk.y, gb.y);
        t2v.z = fmaf(-gam.z, pv.z - pk.z, gb.z);
        t2v.w = fmaf(-gam.w, pv.w - pk.w, gb.w);
        *(float4*)&sT2[s * 68 + dt * 4] = t2v;
        short4_t kk; kk[0]=f2bf(pk.x); kk[1]=f2bf(pk.y); kk[2]=f2bf(pk.z); kk[3]=f2bf(pk.w);
        *(short4_t*)&bxk[s * 72 + dt * 4] = kk;
        short4_t qq; qq[0]=f2bf(pq.x); qq[1]=f2bf(pq.y); qq[2]=f2bf(pq.z); qq[3]=f2bf(pq.w);
        *(short4_t*)&bxq[s * 72 + dt * 4] = qq;
        if (t < 64) *(float4*)&sEta[t * 4] = pe;
        pkc = pk;
        __syncthreads();   // (B)

        // prefetch next minibatch (in flight across the whole step)
        if (m + 1 < NMB) {
            const size_t o = (size_t)(m + 1) * (MBS * HD) + t * 4;
            pq = *(const float4*)&xqg[o];
            pk = *(const float4*)&xkg[o];
            pv = *(const float4*)&xvg[o];
            if (t < 64) pe = *(const float4*)&etg[(size_t)(m + 1) * (MBS * MBS) + t * 4];
        }

        // ======== MFMA1: Z1 = xk@W + b1 ; Zq = xq@W + b1 ; Attn = xq@xk^T ========
        const float b1v = sB1[16 * w + lc];
        f32x4 z1a; z1a[0]=b1v; z1a[1]=b1v; z1a[2]=b1v; z1a[3]=b1v;
        f32x4 zqa = z1a;
        const short8 ak0 = *(const short8*)&bxk[lc * 72 + gq * 8];
        const short8 ak1 = *(const short8*)&bxk[lc * 72 + gq * 8 + 32];
        const short8 aq0 = *(const short8*)&bxq[lc * 72 + gq * 8];
        const short8 aq1 = *(const short8*)&bxq[lc * 72 + gq * 8 + 32];
        const short8 bw0 = *(const short8*)&sWt[(16 * w + lc) * 72 + gq * 8];
        const short8 bw1 = *(const short8*)&sWt[(16 * w + lc) * 72 + gq * 8 + 32];
        z1a = MFMA(ak0, bw0, z1a); z1a = MFMA(ak1, bw1, z1a);
        zqa = MFMA(aq0, bw0, zqa); zqa = MFMA(aq1, bw1, zqa);
#pragma unroll
        for (int r = 0; r < 4; ++r) sZ1[(4 * gq + r) * 68 + 16 * w + lc] = z1a[r];
        if (w == 3) {
            f32x4 zz; zz[0]=0.f; zz[1]=0.f; zz[2]=0.f; zz[3]=0.f;
            zz = MFMA(aq0, ak0, zz); zz = MFMA(aq1, ak1, zz);
#pragma unroll
            for (int r = 0; r < 4; ++r) sAttn[(4 * gq + r) * 20 + lc] = zz[r];
        }
        __syncthreads();   // (C)

        // ======== THREAD1: LN-bwd -> g ; stage g^T, (-le*xk)^T, -E ; b1 partials ========
        f32x4 z   = *(f32x4*)&sZ1[s * 68 + dt * 4];
        f32x4 t2r = *(f32x4*)&sT2[s * 68 + dt * 4];
        float sum = z[0] + z[1] + z[2] + z[3];
        float sq  = z[0]*z[0] + z[1]*z[1] + z[2]*z[2] + z[3]*z[3];
#pragma unroll
        for (int msk = 1; msk < 16; msk <<= 1) {
            sum += __shfl_xor(sum, msk);
            sq  += __shfl_xor(sq, msk);
        }
        const float mu   = sum * (1.f / 64.f);
        const float rstd = rsqrtf(sq * (1.f / 64.f) - mu * mu + 1e-6f);
        float xh[4], gx[4];
        const float c1a[4] = {c1.x, c1.y, c1.z, c1.w};
        const float t2a[4] = {t2r[0], t2r[1], t2r[2], t2r[3]};
        float r1 = 0.f, r2 = 0.f;
#pragma unroll
        for (int c = 0; c < 4; ++c) {
            xh[c] = (z[c] - mu) * rstd;
            gx[c] = fmaf(c1a[c], xh[c], t2a[c]);
            r1 += gx[c];
            r2 = fmaf(gx[c], xh[c], r2);
        }
#pragma unroll
        for (int msk = 1; msk < 16; msk <<= 1) {
            r1 += __shfl_xor(r1, msk);
            r2 += __shfl_xor(r2, msk);
        }
        const float cf = rstd * (1.f / 64.f);
        float g[4];
#pragma unroll
        for (int c = 0; c < 4; ++c)
            g[c] = (64.f * gx[c] - r1 - xh[c] * r2) * cf;

        const float le = sEta[240 + s];
        // tiled layout: elem = (j>>2)*256 + (d>>4)*64 + (j&3)*16 + (d&15), j=s, d=4dt+c
        const int tb = (s >> 2) * 256 + (dt >> 2) * 64 + (s & 3) * 16 + (dt & 3) * 4;
        short4_t gp;
#pragma unroll
        for (int c = 0; c < 4; ++c) gp[c] = f2bf(g[c]);
        *(short4_t*)&sGt[tb] = gp;
        short4_t kp;
        const float pka[4] = {pkc.x, pkc.y, pkc.z, pkc.w};
#pragma unroll
        for (int c = 0; c < 4; ++c) kp[c] = f2bf(-le * pka[c]);
        *(short4_t*)&sXKe[tb] = kp;

        // b1 partial: sum over the wave's 4 s-rows of le*g
        f32x4 bp;
#pragma unroll
        for (int c = 0; c < 4; ++c) {
            float v = le * g[c];
            v += __shfl_xor(v, 16);
            v += __shfl_xor(v, 32);
            bp[c] = v;
        }
        if (gq == 0) *(f32x4*)&sB1p[w * 64 + dt * 4] = bp;

        // E = tril * eta * (1 + Attn_raw); store -E (cols 0..15; 16..31 stay 0)
        if (dt < 4) {
            f32x4 at = *(f32x4*)&sAttn[s * 20 + dt * 4];
            f32x4 ev = *(f32x4*)&sEta[s * 16 + dt * 4];
            short4_t ep;
#pragma unroll
            for (int c = 0; c < 4; ++c) {
                const int cc = 4 * dt + c;
                ep[c] = f2bf((cc <= s) ? -ev[c] * (1.f + at[c]) : 0.f);
            }
            *(short4_t*)&sE[s * 40 + 4 * dt] = ep;
        }
        __syncthreads();   // (D)

        // ======== MFMA2: Z1_bar = Zq - E@g ; W -= (le*xk)^T @ g ========
        // tr-read: each lane supplies tile_base + 8*lc; HW crossbar delivers
        // column lc of the 4x16 tile. tile(jblk,nblk) byte base = jblk*512 + nblk*128.
        // jblk = 2*gq (+1 via offset:512). gq=2,3 -> jblk 4..7: permanently-zero region.
        const unsigned gbase = (unsigned)(size_t)(&sGt[0]) + 1024u * gq + 8u * lc;
        const unsigned ebase = gbase + 128u * (unsigned)w;                 // g, nblk=w
        const unsigned kbase = (unsigned)(size_t)(&sXKe[0]) + 1024u * gq + 8u * lc
                             + 128u * (unsigned)w;                          // -le*xk, nblk=w
        short4_t elo, ehi, al, ah;
        short4_t bl0, bh0, bl1, bh1, bl2, bh2, bl3, bh3;
        TR_READ(elo, ebase, "0");   TR_READ(ehi, ebase, "512");
        TR_READ(al,  kbase, "0");   TR_READ(ah,  kbase, "512");
        TR_READ(bl0, gbase, "0");   TR_READ(bh0, gbase, "512");
        TR_READ(bl1, gbase, "128"); TR_READ(bh1, gbase, "640");
        TR_READ(bl2, gbase, "256"); TR_READ(bh2, gbase, "768");
        TR_READ(bl3, gbase, "384"); TR_READ(bh3, gbase, "896");
        const short8 aE = *(const short8*)&sE[lc * 40 + gq * 8];
        asm volatile("s_waitcnt lgkmcnt(0)" ::: "memory");
        __builtin_amdgcn_sched_barrier(0);

        f32x4 zb = MFMA(aE, cmb(elo, ehi), zqa);
#pragma unroll
        for (int r = 0; r < 4; ++r) sZb[(4 * gq + r) * 68 + 16 * w + lc] = zb[r];

        const short8 aK = cmb(al, ah);
        Wacc[0] = MFMA(aK, cmb(bl0, bh0), Wacc[0]);
        Wacc[1] = MFMA(aK, cmb(bl1, bh1), Wacc[1]);
        Wacc[2] = MFMA(aK, cmb(bl2, bh2), Wacc[2]);
        Wacc[3] = MFMA(aK, cmb(bl3, bh3), Wacc[3]);
#pragma unroll
        for (int ct = 0; ct < 4; ++ct) {
            short4_t wp;
#pragma unroll
            for (int r = 0; r < 4; ++r) wp[r] = f2bf(Wacc[ct][r]);
            *(short4_t*)&sWt[(16 * ct + lc) * 72 + 16 * w + 4 * gq] = wp;
        }
        __syncthreads();   // (E)

        // ======== THREAD2: LN-fwd + output ; b1 update ========
        f32x4 zbr = *(f32x4*)&sZb[s * 68 + dt * 4];
        float sb  = zbr[0] + zbr[1] + zbr[2] + zbr[3];
        float sb2 = zbr[0]*zbr[0] + zbr[1]*zbr[1] + zbr[2]*zbr[2] + zbr[3]*zbr[3];
#pragma unroll
        for (int msk = 1; msk < 16; msk <<= 1) {
            sb  += __shfl_xor(sb, msk);
            sb2 += __shfl_xor(sb2, msk);
        }
        const float mu2   = sb * (1.f / 64.f);
        const float rstd2 = rsqrtf(sb2 * (1.f / 64.f) - mu2 * mu2 + 1e-6f);
        f32x4 xq4 = *(f32x4*)&sXQ[s * 68 + dt * 4];
        const float ga[4] = {gam.x, gam.y, gam.z, gam.w};
        const float ba[4] = {bet.x, bet.y, bet.z, bet.w};
        float o[4];
#pragma unroll
        for (int c = 0; c < 4; ++c)
            o[c] = xq4[c] + fmaf(ga[c], (zbr[c] - mu2) * rstd2, ba[c]);
        const size_t oi = ((size_t)b * 4096 + (size_t)m * 16 + s) * 512 + h * 64 + dt * 4;
        *(float4*)&gOUT[oi] = make_float4(o[0], o[1], o[2], o[3]);

        if (t < 64) {
            const float bsum = sB1p[t] + sB1p[64 + t] + sB1p[128 + t] + sB1p[192 + t];
            sB1[t] -= bsum;
        }
    }
}

extern "C" void kernel_launch(void* const* d_in, const int* in_sizes, int n_in,
                              void* d_out, int out_size, void* d_ws, size_t ws_size,
                              hipStream_t stream) {
    const float* XQ  = (const float*)d_in[0];
    const float* XK  = (const float*)d_in[1];
    const float* XV  = (const float*)d_in[2];
    const float* ETA = (const float*)d_in[3];
    const float* W1  = (const float*)d_in[4];
    const float* B1  = (const float*)d_in[5];
    const float* LNW = (const float*)d_in[6];
    const float* LNB = (const float*)d_in[7];
    float* OUT = (float*)d_out;

    const int n_chains = in_sizes[0] / (NMB * MBS * HD);   // B*nh = 64
    ttt_scan<<<n_chains, 256, 0, stream>>>(XQ, XK, XV, ETA, W1, B1, LNW, LNB, OUT);
}